// Round 6
// baseline (281.539 us; speedup 1.0000x reference)
//
#include <hip/hip_runtime.h>

#define N_B   262144
#define BM    96       // 96 rows/block: acc=96 regs frees 3-deep mfrag rotate (R3 spilled at acc=128)
#define NBLK  2731     // 2730*96 + 64-row tail block
#define KAUG  288      // 256 (h) + 32 (x-augmentation, only 3 used)
#define LDA   264      // hA row stride in halves: 528B = 33*16B; 132 dw = 4 mod 32 (2/4-way alias, ~1% cost)

typedef _Float16 f16x8 __attribute__((ext_vector_type(8)));
typedef _Float16 f16x4 __attribute__((ext_vector_type(4)));
typedef float    f32x4 __attribute__((ext_vector_type(4)));
typedef float    f32x16 __attribute__((ext_vector_type(16)));

// ---------------------------------------------------------------------------
// Precompute (68 blocks, ~5 us):
//   blocks 0..63 : (l = b>>4, row-group ng = b&15) -> Mt[l][16ng..16ng+16)[*]
//   blocks 64..67: W1t[n][k] = W1[k][n] transpose.
// ---------------------------------------------------------------------------
__global__ void fno_precompute(const float* __restrict__ W1,
                               const float* __restrict__ fw,
                               const float* __restrict__ lw,
                               _Float16* __restrict__ Mt,    // [4][256][KAUG]
                               _Float16* __restrict__ W1t)   // [256][64]
{
    const int t = threadIdx.x;          // 0..255
    const int b = blockIdx.x;
    if (b < 64) {
        const int l  = b >> 4;
        const int ng = b & 15;
        __shared__ float cosTab[256];
        __shared__ float cs[256];
        cosTab[t] = cosf((float)t * (6.28318530717958647692f / 256.0f));
        __syncthreads();
        // cs[t] = irfft(fw_l)[t]
        {
            const float* fwl = fw + l * 129;
            float s = fwl[0];
            #pragma unroll 4
            for (int k = 1; k < 128; ++k)
                s += 2.0f * fwl[k] * cosTab[(k * t) & 255];
            s += fwl[128] * ((t & 1) ? -1.0f : 1.0f);
            cs[t] = s * (1.0f / 256.0f);
        }
        __syncthreads();
        for (int idx = t; idx < 16 * KAUG; idx += 256) {
            const int n = ng * 16 + idx / KAUG;
            const int k = idx % KAUG;
            float v = 0.0f;
            if (k < 253)               v = cs[(n - k - 3) & 255];  // conv: h[k] -> d[k+3]
            if (k == n)                v += lw[l * 256 + n];       // diagonal residual lw
            if (k >= 256 && k < 259)   v = cs[(n - (k - 256)) & 255]; // x rows
            Mt[((size_t)l * 256 + n) * KAUG + k] = (_Float16)v;
        }
    } else {
        const int base = (b - 64) * 4096;
        #pragma unroll
        for (int i = 0; i < 16; ++i) {
            const int idx = base + t + i * 256;
            const int n = idx >> 6, k = idx & 63;
            W1t[idx] = (_Float16)W1[k * 256 + n];
        }
    }
}

// ---------------------------------------------------------------------------
// Fused main kernel. Block = 96 rows x 256 threads (4 waves); wave w owns
// feature columns [64w, 64w+64); 32x32x16 MFMA, acc[2][3] = 96 regs.
// KEY CHANGE vs R4: mfrag loads are pipelined 3 kc-steps ahead through a
// static 3-slot register rotate (A/B/C, 24 regs). R2/R4 counters showed ~1
// exposed L2 latency (~250cyc) per kc-step; R3's rotate at BM=128 spilled
// (acc 128 + 32 rotate > 256). BM=96 frees the registers: 96+24+~60 < 256.
// kc=17 deleted (Mt cols 272..287 are exactly zero -> 8 wasted MFMA/wave).
// Next-layer chunks 0..2 prefetch before the epilogue barrier (no hA dep).
// x-augmentation in hA cols 256..258: kc=16 reads cols 256..271 =
// x + zeros + next-row over-read against exactly-zero Mt weights; 24-half
// zeroed pad after hA keeps row 95's over-read finite.
// Tail block (#2730, 64 valid rows): staging row index clamped (finite
// garbage rows, never stored), stores guarded.
// ---------------------------------------------------------------------------

#define KSTEP(M0, M1, KB)                                                   \
    { _Pragma("unroll")                                                     \
      for (int rt = 0; rt < 3; ++rt) {                                      \
          f16x8 hfrag = *(const f16x8*)&hA[hoff + 32 * rt * LDA + (KB)];    \
          acc[0][rt] = __builtin_amdgcn_mfma_f32_32x32x16_f16(              \
              M0, hfrag, acc[0][rt], 0, 0, 0);                              \
          acc[1][rt] = __builtin_amdgcn_mfma_f32_32x32x16_f16(              \
              M1, hfrag, acc[1][rt], 0, 0, 0);                              \
      } }

#define LDM(M0, M1, PTR, KB)                                                \
    { M0 = *(const f16x8*)((PTR) + (KB));                                   \
      M1 = *(const f16x8*)((PTR) + 32 * KAUG + (KB)); }

#define LDMW(M0, M1, KB)                                                    \
    { M0 = *(const f16x8*)(W1p + (KB));                                     \
      M1 = *(const f16x8*)(W1p + 32 * 64 + (KB)); }

__global__ __launch_bounds__(256, 2)
void fno_main(const float* __restrict__ mu,
              const float* __restrict__ x,
              const float* __restrict__ b1,
              const float* __restrict__ W2,
              const float* __restrict__ b2,
              const _Float16* __restrict__ Mt,
              const _Float16* __restrict__ W1t,
              float* __restrict__ out)
{
    __shared__ __align__(16) _Float16 hA[BM * LDA + 24];  // + zeroed over-read pad
    __shared__ float b1s[256];
    __shared__ float W2s[256];
    __shared__ float red[BM];

    const int t    = threadIdx.x;
    const int w    = t >> 6;        // wave id: feature stripe 64*w
    const int lane = t & 63;
    const int i32  = lane & 31;     // operand index: h-row / Mt-feat
    const int q2   = lane >> 5;     // k-half within a K=16 chunk
    const int r0   = blockIdx.x * BM;
    const int hoff = i32 * LDA + 8 * q2;   // hfrag base offset (halves)

    // ---- stage mu -> hA cols 0..63 (fp16); x -> cols 256..263; zero pad ----
    {
        const float4* mu4 = (const float4*)mu;
        #pragma unroll
        for (int j = 0; j < 6; ++j) {
            int f = t + 256 * j;                 // 0..1535 = 96 rows * 16
            int row = f >> 4, c4 = f & 15;
            int g = r0 + row; if (g > N_B - 1) g = N_B - 1;   // tail clamp
            float4 v = mu4[(size_t)g * 16 + c4];
            f16x4 h;
            h[0] = (_Float16)v.x; h[1] = (_Float16)v.y;
            h[2] = (_Float16)v.z; h[3] = (_Float16)v.w;
            *(f16x4*)&hA[row * LDA + c4 * 4] = h;
        }
        if (t < BM) {
            int g = r0 + t; if (g > N_B - 1) g = N_B - 1;
            const float* xp = x + (size_t)g * 3;
            f16x8 hx = {(_Float16)xp[0], (_Float16)xp[1], (_Float16)xp[2],
                        (_Float16)0, (_Float16)0, (_Float16)0,
                        (_Float16)0, (_Float16)0};
            *(f16x8*)&hA[t * LDA + 256] = hx;
        }
        if (t < 3) {                    // zero the 24-half pad (row-95 over-read)
            f16x8 z8 = {};
            *(f16x8*)&hA[BM * LDA + 8 * t] = z8;
        }
        b1s[t] = b1[t];
        W2s[t] = W2[t];
    }

    // encoder mfrag prefetch (issues before the staging barrier; no LDS dep)
    const _Float16* W1p = W1t + (64 * w + i32) * 64 + 8 * q2;
    f16x8 mA0, mA1, mB0, mB1, mC0, mC1;
    LDMW(mA0, mA1, 0)
    LDMW(mB0, mB1, 16)
    LDMW(mC0, mC1, 32)
    __syncthreads();

    const f32x16 fz = {0.f,0.f,0.f,0.f, 0.f,0.f,0.f,0.f,
                       0.f,0.f,0.f,0.f, 0.f,0.f,0.f,0.f};
    f32x16 acc[2][3];   // [feature-tile(32)][row-tile(32)], 96 regs

    // ================= encoder: h = relu(mu @ W1 + b1), K = 64 =================
    #pragma unroll
    for (int ft = 0; ft < 2; ++ft)
        #pragma unroll
        for (int rt = 0; rt < 3; ++rt) acc[ft][rt] = fz;

    KSTEP(mA0, mA1, 0)   LDMW(mA0, mA1, 48)
    KSTEP(mB0, mB1, 16)
    KSTEP(mC0, mC1, 32)
    KSTEP(mA0, mA1, 48)

    // prefetch layer-0 chunks 0..2 (no hA dependency -> overlaps barrier+epilogue)
    {
        const _Float16* M0p = Mt + (size_t)(64 * w + i32) * KAUG + 8 * q2;
        LDM(mA0, mA1, M0p, 0)
        LDM(mB0, mB1, M0p, 16)
        LDM(mC0, mC1, M0p, 32)
    }
    __syncthreads();   // all reads of mu-region done before overwrite
    #pragma unroll
    for (int ft = 0; ft < 2; ++ft)
        #pragma unroll
        for (int rt = 0; rt < 3; ++rt) {
            const int row = 32 * rt + i32;
            #pragma unroll
            for (int rg = 0; rg < 4; ++rg) {
                const int fb = 64 * w + 32 * ft + 4 * q2 + 8 * rg;
                const float4 bias = *(const float4*)&b1s[fb];
                f16x4 hv;
                hv[0] = (_Float16)fmaxf(acc[ft][rt][4 * rg + 0] + bias.x, 0.f);
                hv[1] = (_Float16)fmaxf(acc[ft][rt][4 * rg + 1] + bias.y, 0.f);
                hv[2] = (_Float16)fmaxf(acc[ft][rt][4 * rg + 2] + bias.z, 0.f);
                hv[3] = (_Float16)fmaxf(acc[ft][rt][4 * rg + 3] + bias.w, 0.f);
                *(f16x4*)&hA[row * LDA + fb] = hv;
            }
        }

    // ================= 4 Fourier layers: h = relu([h|x] @ M_l) ================
    #pragma unroll 1
    for (int l = 0; l < 4; ++l) {
        __syncthreads();   // hA writes from previous stage visible
        #pragma unroll
        for (int ft = 0; ft < 2; ++ft)
            #pragma unroll
            for (int rt = 0; rt < 3; ++rt) acc[ft][rt] = fz;

        const _Float16* Mlp = Mt + ((size_t)l * 256 + 64 * w + i32) * KAUG + 8 * q2;

        // 17 kc-steps, 3-slot rotate; mfrag for kc loaded at kc-3 (~200cyc lead)
        KSTEP(mA0, mA1,   0)  LDM(mA0, mA1, Mlp,  48)
        KSTEP(mB0, mB1,  16)  LDM(mB0, mB1, Mlp,  64)
        KSTEP(mC0, mC1,  32)  LDM(mC0, mC1, Mlp,  80)
        KSTEP(mA0, mA1,  48)  LDM(mA0, mA1, Mlp,  96)
        KSTEP(mB0, mB1,  64)  LDM(mB0, mB1, Mlp, 112)
        KSTEP(mC0, mC1,  80)  LDM(mC0, mC1, Mlp, 128)
        KSTEP(mA0, mA1,  96)  LDM(mA0, mA1, Mlp, 144)
        KSTEP(mB0, mB1, 112)  LDM(mB0, mB1, Mlp, 160)
        KSTEP(mC0, mC1, 128)  LDM(mC0, mC1, Mlp, 176)
        KSTEP(mA0, mA1, 144)  LDM(mA0, mA1, Mlp, 192)
        KSTEP(mB0, mB1, 160)  LDM(mB0, mB1, Mlp, 208)
        KSTEP(mC0, mC1, 176)  LDM(mC0, mC1, Mlp, 224)
        KSTEP(mA0, mA1, 192)  LDM(mA0, mA1, Mlp, 240)
        KSTEP(mB0, mB1, 208)  LDM(mB0, mB1, Mlp, 256)
        KSTEP(mC0, mC1, 224)
        KSTEP(mA0, mA1, 240)
        KSTEP(mB0, mB1, 256)   // kc=16: x cols + zeros + next-row (zero weights)

        if (l < 3) {           // prefetch next layer's kc 0..2 across the barrier
            const _Float16* Mn = Mlp + 256 * KAUG;
            LDM(mA0, mA1, Mn, 0)
            LDM(mB0, mB1, Mn, 16)
            LDM(mC0, mC1, Mn, 32)
        }

        __syncthreads();   // all hA reads done before overwrite
        #pragma unroll
        for (int ft = 0; ft < 2; ++ft)
            #pragma unroll
            for (int rt = 0; rt < 3; ++rt) {
                const int row = 32 * rt + i32;
                #pragma unroll
                for (int rg = 0; rg < 4; ++rg) {
                    const int fb = 64 * w + 32 * ft + 4 * q2 + 8 * rg;
                    f16x4 hv;
                    hv[0] = (_Float16)fmaxf(acc[ft][rt][4 * rg + 0], 0.f);
                    hv[1] = (_Float16)fmaxf(acc[ft][rt][4 * rg + 1], 0.f);
                    hv[2] = (_Float16)fmaxf(acc[ft][rt][4 * rg + 2], 0.f);
                    hv[3] = (_Float16)fmaxf(acc[ft][rt][4 * rg + 3], 0.f);
                    *(f16x4*)&hA[row * LDA + fb] = hv;
                }
            }
    }

    // ================= decoder: out = h @ W2 + b2 =============================
    __syncthreads();
    {
        const int r    = t >> 1;        // two threads per row
        const int half = t & 1;
        float s = 0.f;
        if (t < 2 * BM) {
            const int n0 = half * 128;
            #pragma unroll
            for (int j = 0; j < 16; ++j) {
                f16x8 v = *(const f16x8*)&hA[r * LDA + n0 + 8 * j];
                const float* wp = &W2s[n0 + 8 * j];
                s += (float)v[0] * wp[0] + (float)v[1] * wp[1]
                   + (float)v[2] * wp[2] + (float)v[3] * wp[3]
                   + (float)v[4] * wp[4] + (float)v[5] * wp[5]
                   + (float)v[6] * wp[6] + (float)v[7] * wp[7];
            }
            if (half) red[r] = s;
        }
        __syncthreads();
        if (t < 2 * BM && !half && r0 + r < N_B)
            out[r0 + r] = s + red[r] + b2[0];
    }
}

// ---------------------------------------------------------------------------
extern "C" void kernel_launch(void* const* d_in, const int* in_sizes, int n_in,
                              void* d_out, int out_size, void* d_ws, size_t ws_size,
                              hipStream_t stream) {
    const float* mu = (const float*)d_in[0];
    const float* x  = (const float*)d_in[1];
    const float* W1 = (const float*)d_in[2];
    const float* b1 = (const float*)d_in[3];
    const float* fw = (const float*)d_in[4];
    const float* lw = (const float*)d_in[5];
    const float* W2 = (const float*)d_in[6];
    const float* b2 = (const float*)d_in[7];
    float* out = (float*)d_out;

    _Float16* Mt  = (_Float16*)d_ws;
    _Float16* W1t = Mt + 4 * 256 * KAUG;

    fno_precompute<<<68, 256, 0, stream>>>(W1, fw, lw, Mt, W1t);
    fno_main<<<NBLK, 256, 0, stream>>>(mu, x, b1, W2, b2, Mt, W1t, out);
}

// Round 7
// 259.548 us; speedup vs baseline: 1.0847x; 1.0847x over previous
//
#include <hip/hip_runtime.h>

#define N_B   262144
#define BM    128      // proven best tile; 2 blocks/CU
#define KD    256      // K per Fourier layer: 253 conv taps + 3 x-slots (cols 253..255)
#define LDA   264      // hA row stride in halves (528 B); cols 256..259 = h[252..255] stash
#define LDAB  528      // row stride in bytes

typedef _Float16 f16x8 __attribute__((ext_vector_type(8)));
typedef _Float16 f16x4 __attribute__((ext_vector_type(4)));
typedef float    f32x4 __attribute__((ext_vector_type(4)));
typedef float    f32x16 __attribute__((ext_vector_type(16)));

// ---------------------------------------------------------------------------
// Precompute:
//   blocks 0..63 : (l = b>>4, row-group ng = b&15) -> Mt[l][16ng..16ng+16)[*]
//     Mt[n][k], k<253 : cs[(n-k-3)&255] (+ lw[n] if k==n)   [conv taps of h[k]]
//               k=253+j: cs[(n-j)&255]                      [x_j weights]
//     NOTE: diagonal lw[n] for n in {253,254,255} is NOT in Mt (its column is
//     an x-slot now); fno_main applies it as an epilogue fixup.
//   blocks 64..67: W1t[n][k] = W1[k][n] transpose.
// ---------------------------------------------------------------------------
__global__ void fno_precompute(const float* __restrict__ W1,
                               const float* __restrict__ fw,
                               const float* __restrict__ lw,
                               _Float16* __restrict__ Mt,    // [4][256][KD]
                               _Float16* __restrict__ W1t)   // [256][64]
{
    const int t = threadIdx.x;          // 0..255
    const int b = blockIdx.x;
    if (b < 64) {
        const int l  = b >> 4;
        const int ng = b & 15;
        __shared__ float cosTab[256];
        __shared__ float cs[256];
        cosTab[t] = cosf((float)t * (6.28318530717958647692f / 256.0f));
        __syncthreads();
        // cs[t] = irfft(fw_l)[t]
        {
            const float* fwl = fw + l * 129;
            float s = fwl[0];
            #pragma unroll 4
            for (int k = 1; k < 128; ++k)
                s += 2.0f * fwl[k] * cosTab[(k * t) & 255];
            s += fwl[128] * ((t & 1) ? -1.0f : 1.0f);
            cs[t] = s * (1.0f / 256.0f);
        }
        __syncthreads();
        for (int idx = t; idx < 16 * KD; idx += 256) {
            const int n = ng * 16 + (idx >> 8);
            const int k = idx & 255;
            float v;
            if (k < 253) {
                v = cs[(n - k - 3) & 255];
                if (k == n) v += lw[l * 256 + n];
            } else {
                v = cs[(n - (k - 253)) & 255];      // x_j weight, j = k-253
            }
            Mt[((size_t)l * 256 + n) * KD + k] = (_Float16)v;
        }
    } else {
        const int base = (b - 64) * 4096;
        #pragma unroll
        for (int i = 0; i < 16; ++i) {
            const int idx = base + t + i * 256;
            const int n = idx >> 6, k = idx & 63;
            W1t[idx] = (_Float16)W1[k * 256 + n];
        }
    }
}

// ---------------------------------------------------------------------------
// Fused main kernel. Block = 128 rows x 256 threads (4 waves); wave w owns
// feature columns [64w, 64w+64); 32x32x16 MFMA, acc[2][4] = 128 regs.
// CHANGES vs R4 (169us):
//  (1) K = 256 not 272: x lives in cols 253..255 (the cropped-out h slots);
//      h[252..255] stashed UNSWIZZLED at cols 256..259 for the lw-diagonal
//      fixup (feats 253..255, wave 3 only) and the decoder. -6% MFMA/LDS,
//      -11% L2 Mt bytes.
//  (2) LDS XOR-swizzle: 16B-aligned rows give row-stride = 4 dw mod 32 ->
//      rows {r,r+8,r+16,r+24} collide 4-way on every b128 hfrag read
//      (m136: 1.58x). byteoff ^= ((row>>3)&3)<<4 decollides; the xor is
//      lane-constant in the K-loop (32rt contributes 0 mod 4 to row>>3).
//      Applied to ALL accesses in cols 0..255; stash region unswizzled.
// ---------------------------------------------------------------------------
__global__ __launch_bounds__(256, 2)
void fno_main(const float* __restrict__ mu,
              const float* __restrict__ x,
              const float* __restrict__ b1,
              const float* __restrict__ lw,
              const float* __restrict__ W2,
              const float* __restrict__ b2,
              const _Float16* __restrict__ Mt,
              const _Float16* __restrict__ W1t,
              float* __restrict__ out)
{
    __shared__ __align__(16) char hAb[BM * LDAB];   // 67,584 B
    __shared__ float b1s[256];
    __shared__ float W2s[260];    // [0..251]=W2, [252..255]=0, [256..259]=W2[252..255]
    __shared__ float red[BM];

    const int t    = threadIdx.x;
    const int w    = t >> 6;        // wave id: feature stripe 64*w
    const int lane = t & 63;
    const int i32  = lane & 31;     // operand index: h-row / Mt-feat
    const int q2   = lane >> 5;     // k-half within a K=16 chunk
    const int r0   = blockIdx.x * BM;
    const int xrB  = ((i32 >> 3) & 3) << 4;   // lane-constant row swizzle

    // ---- stage mu -> cols 0..63; x -> cols 253..255; b1/W2 -> LDS ----
    {
        const float4* mu4 = (const float4*)mu + (size_t)r0 * 16;
        #pragma unroll
        for (int j = 0; j < 8; ++j) {
            int f = t + 256 * j;
            int row = f >> 4, c4 = f & 15;
            int xr = ((row >> 3) & 3) << 4;
            float4 v = mu4[f];
            f16x4 h;
            h[0] = (_Float16)v.x; h[1] = (_Float16)v.y;
            h[2] = (_Float16)v.z; h[3] = (_Float16)v.w;
            *(f16x4*)(hAb + row * LDAB + ((c4 * 8) ^ xr)) = h;
        }
        if (t < BM) {
            const int row = t;
            const int xr = ((row >> 3) & 3) << 4;
            const float* xp = x + (size_t)(r0 + row) * 3;
            *(_Float16*)(hAb + row * LDAB + (506 ^ xr)) = (_Float16)xp[0]; // col 253
            *(_Float16*)(hAb + row * LDAB + (508 ^ xr)) = (_Float16)xp[1]; // col 254
            *(_Float16*)(hAb + row * LDAB + (510 ^ xr)) = (_Float16)xp[2]; // col 255
        }
        b1s[t] = b1[t];
        W2s[t] = (t < 252) ? W2[t] : 0.0f;
        if (t < 4) W2s[256 + t] = W2[252 + t];
    }
    __syncthreads();

    const f32x16 fz = {0.f,0.f,0.f,0.f, 0.f,0.f,0.f,0.f,
                       0.f,0.f,0.f,0.f, 0.f,0.f,0.f,0.f};
    f32x16 acc[2][4];   // [feature-tile(32)][row-tile(32)], 128 regs

    // ================= encoder: h = relu(mu @ W1 + b1), K = 64 =================
    #pragma unroll
    for (int ft = 0; ft < 2; ++ft)
        #pragma unroll
        for (int rt = 0; rt < 4; ++rt) acc[ft][rt] = fz;

    {
        const _Float16* W1p = W1t + (64 * w + i32) * 64 + 8 * q2;
        #pragma unroll
        for (int kc = 0; kc < 4; ++kc) {
            f16x8 m0 = *(const f16x8*)(W1p + 16 * kc);
            f16x8 m1 = *(const f16x8*)(W1p + 32 * 64 + 16 * kc);
            #pragma unroll
            for (int rt = 0; rt < 4; ++rt) {
                f16x8 hfrag = *(const f16x8*)(hAb + (32 * rt + i32) * LDAB
                                              + ((32 * kc + 16 * q2) ^ xrB));
                acc[0][rt] = __builtin_amdgcn_mfma_f32_32x32x16_f16(m0, hfrag, acc[0][rt], 0, 0, 0);
                acc[1][rt] = __builtin_amdgcn_mfma_f32_32x32x16_f16(m1, hfrag, acc[1][rt], 0, 0, 0);
            }
        }
    }
    __syncthreads();   // all reads of mu-region done before overwrite
    #pragma unroll
    for (int ft = 0; ft < 2; ++ft)
        #pragma unroll
        for (int rt = 0; rt < 4; ++rt) {
            const int row = 32 * rt + i32;
            #pragma unroll
            for (int rg = 0; rg < 4; ++rg) {
                const int fb = 64 * w + 32 * ft + 4 * q2 + 8 * rg;
                const float4 bias = *(const float4*)&b1s[fb];
                f16x4 hv;
                hv[0] = (_Float16)fmaxf(acc[ft][rt][4 * rg + 0] + bias.x, 0.f);
                hv[1] = (_Float16)fmaxf(acc[ft][rt][4 * rg + 1] + bias.y, 0.f);
                hv[2] = (_Float16)fmaxf(acc[ft][rt][4 * rg + 2] + bias.z, 0.f);
                hv[3] = (_Float16)fmaxf(acc[ft][rt][4 * rg + 3] + bias.w, 0.f);
                if (fb == 252) {   // h[252] -> col 252; h[252..255] -> stash (x cols preserved)
                    *(_Float16*)(hAb + row * LDAB + (504 ^ xrB)) = hv[0];
                    *(f16x4*)(hAb + row * LDAB + 512) = hv;
                } else {
                    *(f16x4*)(hAb + row * LDAB + ((fb * 2) ^ xrB)) = hv;
                }
            }
        }

    // ================= 4 Fourier layers: h = relu([h|x] @ M_l + diag fixup) ====
    #pragma unroll 1
    for (int l = 0; l < 4; ++l) {
        __syncthreads();   // hA writes from previous stage visible
        #pragma unroll
        for (int ft = 0; ft < 2; ++ft)
            #pragma unroll
            for (int rt = 0; rt < 4; ++rt) acc[ft][rt] = fz;

        const _Float16* Mlp = Mt + ((size_t)(l * 256 + 64 * w + i32)) * KD + 8 * q2;
        #pragma unroll
        for (int kc = 0; kc < 16; ++kc) {
            f16x8 m0 = *(const f16x8*)(Mlp + 16 * kc);
            f16x8 m1 = *(const f16x8*)(Mlp + 32 * KD + 16 * kc);
            #pragma unroll
            for (int rt = 0; rt < 4; ++rt) {
                f16x8 hfrag = *(const f16x8*)(hAb + (32 * rt + i32) * LDAB
                                              + ((32 * kc + 16 * q2) ^ xrB));
                acc[0][rt] = __builtin_amdgcn_mfma_f32_32x32x16_f16(m0, hfrag, acc[0][rt], 0, 0, 0);
                acc[1][rt] = __builtin_amdgcn_mfma_f32_32x32x16_f16(m1, hfrag, acc[1][rt], 0, 0, 0);
            }
        }

        // diagonal fixup: feats 253..255 (= acc[1][rt][13..15] on wave 3, q2=1)
        // reads h_prev[252..255] from the unswizzled stash BEFORE the barrier.
        if (w == 3 && q2 == 1) {
            const float* lwp = lw + l * 256 + 253;
            const float lw0 = lwp[0], lw1 = lwp[1], lw2 = lwp[2];
            #pragma unroll
            for (int rt = 0; rt < 4; ++rt) {
                f16x4 hp = *(const f16x4*)(hAb + (32 * rt + i32) * LDAB + 512);
                acc[1][rt][13] += lw0 * (float)hp[1];
                acc[1][rt][14] += lw1 * (float)hp[2];
                acc[1][rt][15] += lw2 * (float)hp[3];
            }
        }

        __syncthreads();   // all hA reads done before overwrite
        #pragma unroll
        for (int ft = 0; ft < 2; ++ft)
            #pragma unroll
            for (int rt = 0; rt < 4; ++rt) {
                const int row = 32 * rt + i32;
                #pragma unroll
                for (int rg = 0; rg < 4; ++rg) {
                    const int fb = 64 * w + 32 * ft + 4 * q2 + 8 * rg;
                    f16x4 hv;
                    hv[0] = (_Float16)fmaxf(acc[ft][rt][4 * rg + 0], 0.f);
                    hv[1] = (_Float16)fmaxf(acc[ft][rt][4 * rg + 1], 0.f);
                    hv[2] = (_Float16)fmaxf(acc[ft][rt][4 * rg + 2], 0.f);
                    hv[3] = (_Float16)fmaxf(acc[ft][rt][4 * rg + 3], 0.f);
                    if (fb == 252) {
                        *(_Float16*)(hAb + row * LDAB + (504 ^ xrB)) = hv[0];
                        *(f16x4*)(hAb + row * LDAB + 512) = hv;
                    } else {
                        *(f16x4*)(hAb + row * LDAB + ((fb * 2) ^ xrB)) = hv;
                    }
                }
            }
    }

    // ================= decoder: out = h @ W2 + b2 =============================
    __syncthreads();
    {
        const int r  = t & 127;
        const int hf = t >> 7;        // two threads per row, half the columns each
        const int n0 = hf * 128;
        const int xr = ((r >> 3) & 3) << 4;
        float s = 0.f;
        #pragma unroll
        for (int j = 0; j < 16; ++j) {
            f16x8 v = *(const f16x8*)(hAb + r * LDAB + (((n0 + 8 * j) * 2) ^ xr));
            const float* wp = &W2s[n0 + 8 * j];
            s += (float)v[0] * wp[0] + (float)v[1] * wp[1]
               + (float)v[2] * wp[2] + (float)v[3] * wp[3]
               + (float)v[4] * wp[4] + (float)v[5] * wp[5]
               + (float)v[6] * wp[6] + (float)v[7] * wp[7];
        }
        if (hf) {   // feats 252..255 live in the stash (cols 252..255 zero-weighted)
            f16x4 st = *(const f16x4*)(hAb + r * LDAB + 512);
            s += (float)st[0] * W2s[256] + (float)st[1] * W2s[257]
               + (float)st[2] * W2s[258] + (float)st[3] * W2s[259];
            red[r] = s;
        }
        __syncthreads();
        if (!hf) out[r0 + r] = s + red[r] + b2[0];
    }
}

// ---------------------------------------------------------------------------
extern "C" void kernel_launch(void* const* d_in, const int* in_sizes, int n_in,
                              void* d_out, int out_size, void* d_ws, size_t ws_size,
                              hipStream_t stream) {
    const float* mu = (const float*)d_in[0];
    const float* x  = (const float*)d_in[1];
    const float* W1 = (const float*)d_in[2];
    const float* b1 = (const float*)d_in[3];
    const float* fw = (const float*)d_in[4];
    const float* lw = (const float*)d_in[5];
    const float* W2 = (const float*)d_in[6];
    const float* b2 = (const float*)d_in[7];
    float* out = (float*)d_out;

    _Float16* Mt  = (_Float16*)d_ws;
    _Float16* W1t = Mt + 4 * 256 * KD;

    fno_precompute<<<68, 256, 0, stream>>>(W1, fw, lw, Mt, W1t);
    fno_main<<<N_B / BM, 256, 0, stream>>>(mu, x, b1, lw, W2, b2, Mt, W1t, out);
}